// Round 3
// baseline (1944.136 us; speedup 1.0000x reference)
//
#include <hip/hip_runtime.h>

// CfC recurrence. Round 3:
//  - Prepass on all 256 CUs: px[bg][t][col][row16] = x @ Wbb[0:64,:] + b_bb (fp32,
//    268 MB in d_ws). Recurrence GEMM1 becomes h-only (K=128, 8 MFMAs/wave) with
//    az initialized from a far-prefetched global px load. x stays fp32 (accuracy+).
//  - GEMM2 head-split: ff1/ff2 chains finish first; tanh(ff1/ff2) interleaved with
//    the t-head's MFMA chain so transc issue hides in the MFMA shadow.
//  - LDS-only barriers, wave-rotated GEMM2 k-chunks (round 2) retained.
//  - Fallback to round-2 kernel if ws_size too small for px.

typedef __bf16 bf16;
typedef __bf16 bf16x8 __attribute__((ext_vector_type(8)));
typedef float  f32x4  __attribute__((ext_vector_type(4)));

#define BDIM 512

constexpr int B_  = 256;
constexpr int T_  = 1024;
constexpr int I_  = 64;
constexpr int U_  = 128;
constexpr int BB_ = 256;
constexpr int ROWS = 16;
constexpr int NBLK = B_ / ROWS;        // 16 recurrence blocks
constexpr int KO1  = (I_ + U_) / 8;    // fallback A-octets

__device__ __forceinline__ float tanh_fast(float x) {
  float e = __builtin_amdgcn_exp2f(x * 2.8853900817779268f);
  return 1.0f - 2.0f * __builtin_amdgcn_rcpf(e + 1.0f);
}
__device__ __forceinline__ float sigmoid_fast(float x) {
  return __builtin_amdgcn_rcpf(1.0f + __builtin_amdgcn_exp2f(x * -1.4426950408889634f));
}
__device__ __forceinline__ void barrier_lds() {
  asm volatile("s_waitcnt lgkmcnt(0)" ::: "memory");
  __builtin_amdgcn_s_barrier();
}

// ---------------------------------------------------------------------------
// Prepass: px[(bg*1024+t)*256 + c][r] = sum_k x[bg*16+r][t][k]*Wbb[k][c] + bbb[c]
// One block per (bg,t) tile: 256 threads = 256 cols, 16 rows each, K=64 fp32.
// ---------------------------------------------------------------------------
__global__ __launch_bounds__(256)
void cfc_prepass(const float* __restrict__ x, const float* __restrict__ Wbb,
                 const float* __restrict__ bbb, float* __restrict__ px)
{
  __shared__ float xs[16][64];   // 4 KB
  const int g  = blockIdx.x;               // bg*1024 + t
  const int bg = g >> 10, t = g & 1023;
  const int tid = threadIdx.x;

  // stage x tile: row = tid>>4, cols (tid&15)*4 .. +3
  {
    const int r = tid >> 4, k4 = (tid & 15) * 4;
    float4 v = *(const float4*)(x + ((size_t)(bg * ROWS + r) * T_ + t) * I_ + k4);
    *(float4*)&xs[r][k4] = v;
  }

  // W column c = tid in regs (L2-hot: 64 KB total, reused by all 16384 blocks)
  float wcol[64];
  #pragma unroll
  for (int k = 0; k < 64; k++) wcol[k] = Wbb[k * BB_ + tid];

  float acc[16];
  const float bb = bbb[tid];
  #pragma unroll
  for (int r = 0; r < 16; r++) acc[r] = bb;

  __syncthreads();

  #pragma unroll
  for (int k4 = 0; k4 < 16; k4++) {
    #pragma unroll
    for (int r = 0; r < 16; r++) {
      float4 xq = *(const float4*)&xs[r][k4 * 4];
      acc[r] += xq.x * wcol[k4 * 4]     + xq.y * wcol[k4 * 4 + 1]
              + xq.z * wcol[k4 * 4 + 2] + xq.w * wcol[k4 * 4 + 3];
    }
  }

  float* dst = px + ((size_t)g * BB_ + tid) * ROWS;
  #pragma unroll
  for (int r4 = 0; r4 < 4; r4++) {
    float4 v = { acc[r4 * 4], acc[r4 * 4 + 1], acc[r4 * 4 + 2], acc[r4 * 4 + 3] };
    *(float4*)(dst + r4 * 4) = v;
  }
}

// ---------------------------------------------------------------------------
// Main recurrence (px path): GEMM1 h-only K=128; az init from px.
// ---------------------------------------------------------------------------
__global__ __launch_bounds__(BDIM, 2)
void cfc_main_px(const float* __restrict__ px,
                 const float* __restrict__ Wbb,
                 const float* __restrict__ Wff1, const float* __restrict__ bff1,
                 const float* __restrict__ Wff2, const float* __restrict__ bff2,
                 const float* __restrict__ Wta,  const float* __restrict__ bta,
                 const float* __restrict__ Wtb,  const float* __restrict__ btb,
                 float* __restrict__ out)
{
  __shared__ __align__(16) bf16 Abuf[16 * ROWS * 8];    // h fragments, K=128, 4 KB
  __shared__ __align__(16) bf16 Zbuf[32 * ROWS * 8];    // z, K=256, 8 KB

  const int tid  = threadIdx.x;
  const int w    = tid >> 6;
  const int l    = tid & 63;
  const int quad = l >> 4;
  const int l16  = l & 15;
  const int bg   = blockIdx.x;

  const int c1 = w * 32 + l16;     // GEMM1 col (+0/+16)
  const int u  = w * 16 + l16;     // GEMM2 unit

  // GEMM1 B-fragments: h-part of W_bb only (rows 64..191)
  bf16x8 f1[4][2];
  #pragma unroll
  for (int ks = 0; ks < 4; ks++)
    #pragma unroll
    for (int nt = 0; nt < 2; nt++)
      #pragma unroll
      for (int j = 0; j < 8; j++) {
        int k = 64 + ks * 32 + quad * 8 + j;
        f1[ks][nt][j] = (bf16)Wbb[k * BB_ + c1 + nt * 16];
      }

  // GEMM2 weights, wave-rotated (r=0 = own chunk)
  bf16x8 g2[8][3];
  #pragma unroll
  for (int r = 0; r < 8; r++) {
    int ks = (w + r) & 7;
    #pragma unroll
    for (int j = 0; j < 8; j++) {
      int k = ks * 32 + quad * 8 + j;
      g2[r][0][j] = (bf16)Wff1[k * U_ + u];
      g2[r][1][j] = (bf16)Wff2[k * U_ + u];
      g2[r][2][j] = (bf16)(Wta[k * U_ + u] + Wtb[k * U_ + u]);
    }
  }

  const float bh0 = bff1[u];
  const float bh1 = bff2[u];
  const float bh2 = bta[u] + btb[u];

  // zero h buffer (h0 = 0)
  for (int idx = tid; idx < 16 * ROWS * 8; idx += BDIM) Abuf[idx] = (bf16)0.0f;

  // px addressing: px + ((bg*1024 + t)*256 + c)*16 + quad*4, float4
  const float* pxb = px + (size_t)bg * T_ * BB_ * ROWS / 16 * 16;   // bg*1024*4096
  const size_t o0 = (size_t)c1 * ROWS + quad * 4;
  const size_t o1 = (size_t)(c1 + 16) * ROWS + quad * 4;

  float4 pxv0 = *(const float4*)(pxb + o0);      // t = 0
  float4 pxv1 = *(const float4*)(pxb + o1);

  __syncthreads();

  float* outp  = out + (size_t)(bg * ROWS) * T_ * U_ + u;
  float* hlast = out + (size_t)B_ * T_ * U_ + (size_t)(bg * ROWS) * U_ + u;

  const int h_oct = u >> 3, h_sub = u & 7;
  float hreg[4];

  for (int t = 0; t < T_; ++t) {
    // far prefetch px(t+1)
    const int tn = (t + 1 < T_) ? (t + 1) : (T_ - 1);
    float4 nx0 = *(const float4*)(pxb + (size_t)tn * BB_ * ROWS + o0);
    float4 nx1 = *(const float4*)(pxb + (size_t)tn * BB_ * ROWS + o1);

    // ---- GEMM1 (h-only): az = px + h @ Wbb_h ----
    f32x4 az0 = { pxv0.x, pxv0.y, pxv0.z, pxv0.w };
    f32x4 az1 = { pxv1.x, pxv1.y, pxv1.z, pxv1.w };
    #pragma unroll
    for (int ks = 0; ks < 4; ks++) {
      bf16x8 a = *(const bf16x8*)&Abuf[((ks * 4 + quad) * ROWS + l16) * 8];
      az0 = __builtin_amdgcn_mfma_f32_16x16x32_bf16(a, f1[ks][0], az0, 0, 0, 0);
      az1 = __builtin_amdgcn_mfma_f32_16x16x32_bf16(a, f1[ks][1], az1, 0, 0, 0);
    }
    #pragma unroll
    for (int i = 0; i < 4; i++) {
      int m = quad * 4 + i;
      float z0 = 1.7159f * tanh_fast(0.666f * az0[i]);
      float z1 = 1.7159f * tanh_fast(0.666f * az1[i]);
      Zbuf[((c1 >> 3) * ROWS + m) * 8 + (c1 & 7)] = (bf16)z0;
      Zbuf[(((c1 + 16) >> 3) * ROWS + m) * 8 + ((c1 + 16) & 7)] = (bf16)z1;
    }

    // ---- GEMM2 prologue: own chunk, pre-barrier ----
    f32x4 a0 = { bh0, bh0, bh0, bh0 };
    f32x4 a1 = { bh1, bh1, bh1, bh1 };
    f32x4 a2 = { bh2, bh2, bh2, bh2 };
    {
      bf16x8 zf = *(const bf16x8*)&Zbuf[((w * 4 + quad) * ROWS + l16) * 8];
      a0 = __builtin_amdgcn_mfma_f32_16x16x32_bf16(zf, g2[0][0], a0, 0, 0, 0);
      a1 = __builtin_amdgcn_mfma_f32_16x16x32_bf16(zf, g2[0][1], a1, 0, 0, 0);
      a2 = __builtin_amdgcn_mfma_f32_16x16x32_bf16(zf, g2[0][2], a2, 0, 0, 0);
    }
    barrier_lds();   // barrier 1: z visible

    // ---- GEMM2: ff1/ff2 chains first ----
    #pragma unroll
    for (int r = 1; r < 8; r++) {
      int ks = (w + r) & 7;
      bf16x8 zf = *(const bf16x8*)&Zbuf[((ks * 4 + quad) * ROWS + l16) * 8];
      a0 = __builtin_amdgcn_mfma_f32_16x16x32_bf16(zf, g2[r][0], a0, 0, 0, 0);
      a1 = __builtin_amdgcn_mfma_f32_16x16x32_bf16(zf, g2[r][1], a1, 0, 0, 0);
    }
    // ---- t-head chain interleaved with tanh(ff1/ff2): transc hides in MFMA shadow
    float ff1[4], ff2[4];
    #pragma unroll
    for (int r = 1; r < 8; r++) {
      int ks = (w + r) & 7;
      bf16x8 zf = *(const bf16x8*)&Zbuf[((ks * 4 + quad) * ROWS + l16) * 8];
      a2 = __builtin_amdgcn_mfma_f32_16x16x32_bf16(zf, g2[r][2], a2, 0, 0, 0);
      if (r <= 4) {
        ff1[r - 1] = tanh_fast(a0[r - 1]);
        ff2[r - 1] = tanh_fast(a1[r - 1]);
      }
    }

    // ---- combine ----
    #pragma unroll
    for (int i = 0; i < 4; i++) {
      int m = quad * 4 + i;
      float s = sigmoid_fast(a2[i]);
      float h = ff1[i] + s * (ff2[i] - ff1[i]);
      hreg[i] = h;
      outp[(size_t)m * T_ * U_ + (size_t)t * U_] = h;   // fire-and-forget
      Abuf[(h_oct * ROWS + m) * 8 + h_sub] = (bf16)h;
    }
    pxv0 = nx0; pxv1 = nx1;
    barrier_lds();   // barrier 2: h ready
  }

  #pragma unroll
  for (int i = 0; i < 4; i++)
    hlast[(size_t)(quad * 4 + i) * U_] = hreg[i];
}

// ---------------------------------------------------------------------------
// Fallback (round-2 kernel, x staged in-loop) — used only if ws too small.
// ---------------------------------------------------------------------------
__global__ __launch_bounds__(BDIM, 2)
void cfc_kernel_noPx(const float* __restrict__ x,
                const float* __restrict__ Wbb,  const float* __restrict__ bbb,
                const float* __restrict__ Wff1, const float* __restrict__ bff1,
                const float* __restrict__ Wff2, const float* __restrict__ bff2,
                const float* __restrict__ Wta,  const float* __restrict__ bta,
                const float* __restrict__ Wtb,  const float* __restrict__ btb,
                float* __restrict__ out)
{
  __shared__ __align__(16) bf16 Abuf[KO1 * ROWS * 8];
  __shared__ __align__(16) bf16 Zbuf[32  * ROWS * 8];

  const int tid  = threadIdx.x;
  const int w    = tid >> 6;
  const int l    = tid & 63;
  const int quad = l >> 4;
  const int l16  = l & 15;
  const int bg   = blockIdx.x;

  const int c1 = w * 32 + l16;
  const int u  = w * 16 + l16;

  bf16x8 f1[6][2];
  #pragma unroll
  for (int ks = 0; ks < 6; ks++)
    #pragma unroll
    for (int nt = 0; nt < 2; nt++)
      #pragma unroll
      for (int j = 0; j < 8; j++) {
        int k = ks * 32 + quad * 8 + j;
        f1[ks][nt][j] = (bf16)Wbb[k * BB_ + c1 + nt * 16];
      }

  bf16x8 g2[8][3];
  #pragma unroll
  for (int r = 0; r < 8; r++) {
    int ks = (w + r) & 7;
    #pragma unroll
    for (int j = 0; j < 8; j++) {
      int k = ks * 32 + quad * 8 + j;
      g2[r][0][j] = (bf16)Wff1[k * U_ + u];
      g2[r][1][j] = (bf16)Wff2[k * U_ + u];
      g2[r][2][j] = (bf16)(Wta[k * U_ + u] + Wtb[k * U_ + u]);
    }
  }

  const float bz0 = bbb[c1];
  const float bz1 = bbb[c1 + 16];
  const float bh0 = bff1[u];
  const float bh1 = bff2[u];
  const float bh2 = bta[u] + btb[u];

  for (int idx = tid; idx < (KO1 - 8) * ROWS * 8; idx += BDIM)
    Abuf[8 * ROWS * 8 + idx] = (bf16)0.0f;

  const int xm  = tid >> 5;
  const int xkk = tid & 31;
  const float* xsrc = x + ((size_t)(bg * ROWS + xm) * T_) * I_ + 2 * xkk;
  bf16* xdst = &Abuf[(((2 * xkk) >> 3) * ROWS + xm) * 8 + ((2 * xkk) & 7)];

  {
    float2 v = *(const float2*)xsrc;
    xdst[0] = (bf16)v.x;
    xdst[1] = (bf16)v.y;
  }
  __syncthreads();

  float* outp  = out + (size_t)(bg * ROWS) * T_ * U_ + u;
  float* hlast = out + (size_t)B_ * T_ * U_ + (size_t)(bg * ROWS) * U_ + u;

  const int h_oct = (64 + u) >> 3;
  const int h_sub = (64 + u) & 7;
  float hreg[4];

  for (int t = 0; t < T_; ++t) {
    const int tn = (t + 1 < T_) ? (t + 1) : (T_ - 1);
    float2 xv = *(const float2*)(xsrc + (size_t)tn * I_);

    f32x4 az0 = { bz0, bz0, bz0, bz0 };
    f32x4 az1 = { bz1, bz1, bz1, bz1 };
    #pragma unroll
    for (int ks = 0; ks < 6; ks++) {
      bf16x8 a = *(const bf16x8*)&Abuf[((ks * 4 + quad) * ROWS + l16) * 8];
      az0 = __builtin_amdgcn_mfma_f32_16x16x32_bf16(a, f1[ks][0], az0, 0, 0, 0);
      az1 = __builtin_amdgcn_mfma_f32_16x16x32_bf16(a, f1[ks][1], az1, 0, 0, 0);
    }
    #pragma unroll
    for (int i = 0; i < 4; i++) {
      int m = quad * 4 + i;
      float z0 = 1.7159f * tanh_fast(0.666f * az0[i]);
      float z1 = 1.7159f * tanh_fast(0.666f * az1[i]);
      Zbuf[((c1 >> 3) * ROWS + m) * 8 + (c1 & 7)] = (bf16)z0;
      Zbuf[(((c1 + 16) >> 3) * ROWS + m) * 8 + ((c1 + 16) & 7)] = (bf16)z1;
    }

    f32x4 a0 = { bh0, bh0, bh0, bh0 };
    f32x4 a1 = { bh1, bh1, bh1, bh1 };
    f32x4 a2 = { bh2, bh2, bh2, bh2 };
    {
      bf16x8 zf = *(const bf16x8*)&Zbuf[((w * 4 + quad) * ROWS + l16) * 8];
      a0 = __builtin_amdgcn_mfma_f32_16x16x32_bf16(zf, g2[0][0], a0, 0, 0, 0);
      a1 = __builtin_amdgcn_mfma_f32_16x16x32_bf16(zf, g2[0][1], a1, 0, 0, 0);
      a2 = __builtin_amdgcn_mfma_f32_16x16x32_bf16(zf, g2[0][2], a2, 0, 0, 0);
    }
    barrier_lds();

    #pragma unroll
    for (int r = 1; r < 8; r++) {
      int ks = (w + r) & 7;
      bf16x8 zf = *(const bf16x8*)&Zbuf[((ks * 4 + quad) * ROWS + l16) * 8];
      a0 = __builtin_amdgcn_mfma_f32_16x16x32_bf16(zf, g2[r][0], a0, 0, 0, 0);
      a1 = __builtin_amdgcn_mfma_f32_16x16x32_bf16(zf, g2[r][1], a1, 0, 0, 0);
      a2 = __builtin_amdgcn_mfma_f32_16x16x32_bf16(zf, g2[r][2], a2, 0, 0, 0);
    }

    #pragma unroll
    for (int i = 0; i < 4; i++) {
      int m = quad * 4 + i;
      float ff1 = tanh_fast(a0[i]);
      float ff2 = tanh_fast(a1[i]);
      float s   = sigmoid_fast(a2[i]);
      float h   = ff1 + s * (ff2 - ff1);
      hreg[i]   = h;
      outp[(size_t)m * T_ * U_ + (size_t)t * U_] = h;
      Abuf[(h_oct * ROWS + m) * 8 + h_sub] = (bf16)h;
    }

    xdst[0] = (bf16)xv.x;
    xdst[1] = (bf16)xv.y;

    barrier_lds();
  }

  #pragma unroll
  for (int i = 0; i < 4; i++)
    hlast[(size_t)(quad * 4 + i) * U_] = hreg[i];
}

extern "C" void kernel_launch(void* const* d_in, const int* in_sizes, int n_in,
                              void* d_out, int out_size, void* d_ws, size_t ws_size,
                              hipStream_t stream) {
  const float* x    = (const float*)d_in[0];
  const float* Wbb  = (const float*)d_in[1];
  const float* bbb  = (const float*)d_in[2];
  const float* Wff1 = (const float*)d_in[3];
  const float* bff1 = (const float*)d_in[4];
  const float* Wff2 = (const float*)d_in[5];
  const float* bff2 = (const float*)d_in[6];
  const float* Wta  = (const float*)d_in[7];
  const float* bta  = (const float*)d_in[8];
  const float* Wtb  = (const float*)d_in[9];
  const float* btb  = (const float*)d_in[10];
  float* out = (float*)d_out;
  (void)in_sizes; (void)n_in; (void)out_size;

  const size_t px_bytes = (size_t)B_ * T_ * BB_ * sizeof(float);  // 268 MB
  if (ws_size >= px_bytes) {
    float* px = (float*)d_ws;
    hipLaunchKernelGGL(cfc_prepass, dim3(NBLK * T_), dim3(256), 0, stream,
                       x, Wbb, bbb, px);
    hipLaunchKernelGGL(cfc_main_px, dim3(NBLK), dim3(BDIM), 0, stream,
                       px, Wbb, Wff1, bff1, Wff2, bff2, Wta, bta, Wtb, btb, out);
  } else {
    hipLaunchKernelGGL(cfc_kernel_noPx, dim3(NBLK), dim3(BDIM), 0, stream,
                       x, Wbb, bbb, Wff1, bff1, Wff2, bff2, Wta, bta, Wtb, btb, out);
  }
}